// Round 10
// baseline (106.547 us; speedup 1.0000x reference)
//
#include <hip/hip_runtime.h>
#include <hip/hip_bf16.h>

typedef unsigned short u16;
typedef __attribute__((ext_vector_type(8))) __bf16 bf16x8;
typedef __attribute__((ext_vector_type(8))) unsigned short u16x8;
typedef __attribute__((ext_vector_type(4))) float f32x4;
typedef __attribute__((ext_vector_type(4))) unsigned short u16x4;

#define SEQ 4096
#define DIM 1024
#define NH 16
#define HD 64
#define WIN 256
#define NT32 (SEQ / 32)
#define NKT 32  // K-tiles of 32 in K=1024

__device__ inline u16 f2bf(float f) {
  __hip_bfloat16 h = __float2bfloat16(f);
  return __builtin_bit_cast(u16, h);
}

__device__ inline void gload_lds16(const void* g, void* l) {
  auto gp = reinterpret_cast<__attribute__((address_space(1))) unsigned int*>(
      reinterpret_cast<unsigned long long>(g));
  auto lp = reinterpret_cast<__attribute__((address_space(3))) unsigned int*>(
      reinterpret_cast<unsigned long long>(l));
  __builtin_amdgcn_global_load_lds(gp, lp, 16, 0, 0);
}

__global__ __launch_bounds__(256) void cast4(const float* __restrict__ in,
                                             u16* __restrict__ out, int n) {
  int i = (blockIdx.x * 256 + threadIdx.x) * 4;
  if (i >= n) return;
  const float4 v = *reinterpret_cast<const float4*>(in + i);
  u16x4 r;
  r.x = f2bf(v.x); r.y = f2bf(v.y); r.z = f2bf(v.z); r.w = f2bf(v.w);
  *reinterpret_cast<u16x4*>(out + i) = r;
}

// Fused cast of the 3 weight matrices into Wcat.
__global__ __launch_bounds__(256) void cast_w3(const float* __restrict__ w0, const float* __restrict__ w1,
                                               const float* __restrict__ w2, u16* __restrict__ out) {
  int i = (blockIdx.x * 256 + threadIdx.x) * 4;
  const int seg = i >> 20;                 // 0,1,2
  const int loc = i & ((1 << 20) - 1);
  const float* src = (seg == 0) ? w0 : (seg == 1) ? w1 : w2;
  const float4 v = *reinterpret_cast<const float4*>(src + loc);
  u16x4 r;
  r.x = f2bf(v.x); r.y = f2bf(v.y); r.z = f2bf(v.z); r.w = f2bf(v.w);
  *reinterpret_cast<u16x4*>(out + i) = r;
}

// Pack 3 bias vectors (DIM each) + precomputed mask-add fm[SEQ] (exp2 domain).
__global__ __launch_bounds__(256) void pack_aux(const float* __restrict__ b0, const float* __restrict__ b1,
                                                const float* __restrict__ b2, const float* __restrict__ amask,
                                                float* __restrict__ out) {
  int i = blockIdx.x * 256 + threadIdx.x;  // 0..7167
  if (i < 3072) {
    const int seg = i >> 10, loc = i & 1023;
    out[i] = (seg == 0) ? b0[loc] : (seg == 1) ? b1[loc] : b2[loc];
  } else {
    const int j = i - 3072;
    out[i] = (amask[j] != 0.f) ? -14426.95f : 0.f;   // -10000/ln2
  }
}

// Stage one 256x32 A-panel tile + 256x32 B-panel tile into LDS slot.
__device__ __forceinline__ void stage_tile(const u16* __restrict__ A, const u16* __restrict__ B,
                                           int bm, int bn, u16* sa, u16* sb, int kt, int tid) {
  const int k0 = kt * 32;
#pragma unroll
  for (int l = 0; l < 2; ++l) {
    const int li = l * 512 + tid;         // 1024 chunks of 16B per matrix
    const int r = li >> 2, c = (li & 3) * 8;
    gload_lds16(A + (size_t)(bm + r) * DIM + k0 + c, sa + li * 8);
    gload_lds16(B + (size_t)(bn + r) * DIM + k0 + c, sb + li * 8);
  }
}

// Fused QKV projection, tri-buffered counted-vmcnt pipeline (T3/T4).
// Cols 0-1023    -> Qh [NH][S][64]  (x 0.125/ln2, exp2 trick)
// Cols 1024-2047 -> Kh [NH][S][64]
// Cols 2048-3071 -> Vtile [NH][S/32][64][32], key order sigma-PERMUTED within each 32-tile
//                   to match the zero-shuffle PV fragment in lf_attn.
__global__ __launch_bounds__(512, 2) void gemm_qkv(const u16* __restrict__ A, const u16* __restrict__ B,
                                                   const float* __restrict__ bias,
                                                   u16* __restrict__ Qh, u16* __restrict__ Kh,
                                                   u16* __restrict__ Vtile) {
  __shared__ __align__(16) u16 SA[3][256 * 32];
  __shared__ __align__(16) u16 SB[3][256 * 32];
  const int nwgx = gridDim.x;                        // 12
  const int orig = blockIdx.y * nwgx + blockIdx.x;   // 0..191
  const int cpx = (nwgx * gridDim.y) >> 3;           // 24
  const int wgid = (orig & 7) * cpx + (orig >> 3);   // bijective (192%8==0)
  const int bm = (wgid / nwgx) * 256, bn = (wgid % nwgx) * 256;
  const int tid = threadIdx.x;
  const int lane = tid & 63, wid = tid >> 6;
  const int lrow = lane & 15, lgrp = lane >> 4;
  const int wr = (wid >> 2) * 128, wc = (wid & 3) * 64;

  f32x4 acc[8][4];
  const f32x4 zero = {0.f, 0.f, 0.f, 0.f};
#pragma unroll
  for (int m = 0; m < 8; ++m)
#pragma unroll
    for (int n = 0; n < 4; ++n) acc[m][n] = zero;

  stage_tile(A, B, bm, bn, SA[0], SB[0], 0, tid);
  stage_tile(A, B, bm, bn, SA[1], SB[1], 1, tid);
  asm volatile("s_waitcnt vmcnt(4)" ::: "memory");   // tile0 landed (tile1 may fly)
  asm volatile("s_barrier" ::: "memory");

  for (int t = 0; t < NKT; ++t) {
    const int s = t % 3;
    if (t + 2 < NKT) stage_tile(A, B, bm, bn, SA[(t + 2) % 3], SB[(t + 2) % 3], t + 2, tid);
    bf16x8 af[8], bfr[4];
#pragma unroll
    for (int m = 0; m < 8; ++m)
      af[m] = *reinterpret_cast<const bf16x8*>(&SA[s][(wr + m * 16 + lrow) * 32 + lgrp * 8]);
#pragma unroll
    for (int n = 0; n < 4; ++n)
      bfr[n] = *reinterpret_cast<const bf16x8*>(&SB[s][(wc + n * 16 + lrow) * 32 + lgrp * 8]);
    __builtin_amdgcn_s_setprio(1);
#pragma unroll
    for (int m = 0; m < 8; ++m)
#pragma unroll
      for (int n = 0; n < 4; ++n)
        acc[m][n] = __builtin_amdgcn_mfma_f32_16x16x32_bf16(af[m], bfr[n], acc[m][n], 0, 0, 0);
    __builtin_amdgcn_s_setprio(0);
    if (t + 2 < NKT) { asm volatile("s_waitcnt vmcnt(4)" ::: "memory"); }
    else if (t + 1 < NKT) { asm volatile("s_waitcnt vmcnt(0)" ::: "memory"); }
    asm volatile("s_barrier" ::: "memory");
  }

#pragma unroll
  for (int m = 0; m < 8; ++m)
#pragma unroll
    for (int n = 0; n < 4; ++n) {
      const int row0 = bm + wr + m * 16 + lgrp * 4;
      const int colg = bn + wc + n * 16 + lrow;
      const float b = bias[colg];
      if (bn < 2048) {
        u16* dst = (bn < 1024) ? Qh : Kh;
        const float sc = (bn < 1024) ? 0.18033688f : 1.0f;  // 0.125/ln2 (exp2 trick)
        const int hh = (colg & 1023) >> 6;
        const int dd = colg & 63;
#pragma unroll
        for (int r = 0; r < 4; ++r)
          dst[((size_t)hh * SEQ + row0 + r) * HD + dd] = f2bf((acc[m][n][r] + b) * sc);
      } else {
        const int dv = colg - 2048;
        const int hh = dv >> 6, dd = dv & 63;
        const int k5 = row0 & 31;            // 4-aligned key offset within 32-tile
        const int pos = (k5 < 16) ? ((k5 >> 2) * 8) : (((k5 - 16) >> 2) * 8 + 4);
        u16x4 pk;
#pragma unroll
        for (int r = 0; r < 4; ++r) pk[r] = f2bf(acc[m][n][r] + b);
        u16* vt = Vtile + ((((size_t)hh * NT32 + (row0 >> 5)) * HD + dd) << 5) + pos;
        *reinterpret_cast<u16x4*>(vt) = pk;
      }
    }
}

// Banded flash attention, deferred softmax (exp2), swapped QK^T, zero LDS,
// 64 keys (2 independent 32-key subtiles) per iteration for in-wave ILP.
__global__ __launch_bounds__(256) void lf_attn(const u16* __restrict__ Qh, const u16* __restrict__ Kh,
                                               const u16* __restrict__ Vtile, const float* __restrict__ fm,
                                               float* __restrict__ out) {
  const int nwgx = gridDim.x;                       // 64
  const int nwg = nwgx * gridDim.y;                 // 1024
  const int orig = blockIdx.y * nwgx + blockIdx.x;
  const int cpx = nwg >> 3;                         // 128
  const int wgid = (orig & 7) * cpx + (orig >> 3);  // bijective (1024%8==0)
  const int h = wgid / nwgx;
  const int q0 = (wgid % nwgx) * 64;
  const int tid = threadIdx.x;
  const int wid = tid >> 6, lane = tid & 63;
  const int lrow = lane & 15, lgrp = lane >> 4;
  const int qw = q0 + wid * 16;                     // this wave's 16 q-rows

  bf16x8 qf0, qf1;
  {
    const u16* qbase = Qh + ((size_t)h * SEQ + qw + lrow) * HD + lgrp * 8;
    qf0 = *reinterpret_cast<const bf16x8*>(qbase);
    qf1 = *reinterpret_cast<const bf16x8*>(qbase + 32);
  }
  const f32x4 zero = {0.f, 0.f, 0.f, 0.f};
  f32x4 o_acc[4];
  float psum = 0.f;
#pragma unroll
  for (int g = 0; g < 4; ++g) o_acc[g] = zero;

  int kstart = qw - WIN; if (kstart < 0) kstart = 0; kstart &= ~31;
  int kend = qw + 15 + WIN + 1; kend = (kend + 31) & ~31; if (kend > SEQ) kend = SEQ;

  const int q_abs = qw + lrow;  // this lane's q row (swapped layout)

  const u16* kp = Kh + ((size_t)h * SEQ + kstart + lrow) * HD + lgrp * 8;
  const u16* vp = Vtile + ((size_t)h * NT32 + (kstart >> 5)) * (HD * 32) + lrow * 32 + lgrp * 8;

  // exp + mask + band for one 32-key subtile; updates psum, returns packed bf16 P-frag.
  auto mask_exp = [&](int kt, const f32x4& s0, const f32x4& s1) -> u16x8 {
    u16x8 pu;
    const float4 f0 = *reinterpret_cast<const float4*>(fm + kt + lgrp * 4);
    const float4 f1 = *reinterpret_cast<const float4*>(fm + kt + 16 + lgrp * 4);
    const float f0v[4] = {f0.x, f0.y, f0.z, f0.w};
    const float f1v[4] = {f1.x, f1.y, f1.z, f1.w};
    if (kt >= qw - 241 && kt <= qw + 225) {
#pragma unroll
      for (int r = 0; r < 4; ++r) {
        const float e0 = __builtin_amdgcn_exp2f(s0[r] + f0v[r]);
        const float e1 = __builtin_amdgcn_exp2f(s1[r] + f1v[r]);
        psum += e0 + e1;
        pu[r] = f2bf(e0);
        pu[4 + r] = f2bf(e1);
      }
    } else {
#pragma unroll
      for (int r = 0; r < 4; ++r) {
        const int key0 = kt + lgrp * 4 + r;
        const int d0 = key0 - q_abs + WIN;   // valid iff 0 <= d0 <= 2*WIN
        const float e0 = ((unsigned)d0 <= 2u * WIN) ? __builtin_amdgcn_exp2f(s0[r] + f0v[r]) : 0.f;
        const float e1 = ((unsigned)(d0 + 16) <= 2u * WIN) ? __builtin_amdgcn_exp2f(s1[r] + f1v[r]) : 0.f;
        psum += e0 + e1;
        pu[r] = f2bf(e0);
        pu[4 + r] = f2bf(e1);
      }
    }
    return pu;
  };

  int kt = kstart;
  if (((kend - kstart) >> 5) & 1) {          // odd tile count: one single first
    const bf16x8 kf0 = *reinterpret_cast<const bf16x8*>(kp);
    const bf16x8 kf1 = *reinterpret_cast<const bf16x8*>(kp + 32);
    const bf16x8 kf2 = *reinterpret_cast<const bf16x8*>(kp + 16 * HD);
    const bf16x8 kf3 = *reinterpret_cast<const bf16x8*>(kp + 16 * HD + 32);
    const bf16x8 vf0 = *reinterpret_cast<const bf16x8*>(vp);
    const bf16x8 vf1 = *reinterpret_cast<const bf16x8*>(vp + 512);
    const bf16x8 vf2 = *reinterpret_cast<const bf16x8*>(vp + 1024);
    const bf16x8 vf3 = *reinterpret_cast<const bf16x8*>(vp + 1536);
    kp += 2048; vp += 2048;
    f32x4 s0 = zero, s1 = zero;
    s0 = __builtin_amdgcn_mfma_f32_16x16x32_bf16(kf0, qf0, s0, 0, 0, 0);
    s0 = __builtin_amdgcn_mfma_f32_16x16x32_bf16(kf1, qf1, s0, 0, 0, 0);
    s1 = __builtin_amdgcn_mfma_f32_16x16x32_bf16(kf2, qf0, s1, 0, 0, 0);
    s1 = __builtin_amdgcn_mfma_f32_16x16x32_bf16(kf3, qf1, s1, 0, 0, 0);
    const bf16x8 pa = __builtin_bit_cast(bf16x8, mask_exp(kt, s0, s1));
    o_acc[0] = __builtin_amdgcn_mfma_f32_16x16x32_bf16(pa, vf0, o_acc[0], 0, 0, 0);
    o_acc[1] = __builtin_amdgcn_mfma_f32_16x16x32_bf16(pa, vf1, o_acc[1], 0, 0, 0);
    o_acc[2] = __builtin_amdgcn_mfma_f32_16x16x32_bf16(pa, vf2, o_acc[2], 0, 0, 0);
    o_acc[3] = __builtin_amdgcn_mfma_f32_16x16x32_bf16(pa, vf3, o_acc[3], 0, 0, 0);
    kt += 32;
  }

  for (; kt < kend; kt += 64) {
    // ---- issue ALL loads for both subtiles up front ----
    const bf16x8 kA0 = *reinterpret_cast<const bf16x8*>(kp);
    const bf16x8 kA1 = *reinterpret_cast<const bf16x8*>(kp + 32);
    const bf16x8 kA2 = *reinterpret_cast<const bf16x8*>(kp + 16 * HD);
    const bf16x8 kA3 = *reinterpret_cast<const bf16x8*>(kp + 16 * HD + 32);
    const bf16x8 kB0 = *reinterpret_cast<const bf16x8*>(kp + 2048);
    const bf16x8 kB1 = *reinterpret_cast<const bf16x8*>(kp + 2048 + 32);
    const bf16x8 kB2 = *reinterpret_cast<const bf16x8*>(kp + 2048 + 16 * HD);
    const bf16x8 kB3 = *reinterpret_cast<const bf16x8*>(kp + 2048 + 16 * HD + 32);
    const bf16x8 vA0 = *reinterpret_cast<const bf16x8*>(vp);
    const bf16x8 vA1 = *reinterpret_cast<const bf16x8*>(vp + 512);
    const bf16x8 vA2 = *reinterpret_cast<const bf16x8*>(vp + 1024);
    const bf16x8 vA3 = *reinterpret_cast<const bf16x8*>(vp + 1536);
    const bf16x8 vB0 = *reinterpret_cast<const bf16x8*>(vp + 2048);
    const bf16x8 vB1 = *reinterpret_cast<const bf16x8*>(vp + 2048 + 512);
    const bf16x8 vB2 = *reinterpret_cast<const bf16x8*>(vp + 2048 + 1024);
    const bf16x8 vB3 = *reinterpret_cast<const bf16x8*>(vp + 2048 + 1536);
    kp += 4096; vp += 4096;

    f32x4 sA0 = zero, sA1 = zero, sB0 = zero, sB1 = zero;
    sA0 = __builtin_amdgcn_mfma_f32_16x16x32_bf16(kA0, qf0, sA0, 0, 0, 0);
    sA0 = __builtin_amdgcn_mfma_f32_16x16x32_bf16(kA1, qf1, sA0, 0, 0, 0);
    sA1 = __builtin_amdgcn_mfma_f32_16x16x32_bf16(kA2, qf0, sA1, 0, 0, 0);
    sA1 = __builtin_amdgcn_mfma_f32_16x16x32_bf16(kA3, qf1, sA1, 0, 0, 0);
    sB0 = __builtin_amdgcn_mfma_f32_16x16x32_bf16(kB0, qf0, sB0, 0, 0, 0);
    sB0 = __builtin_amdgcn_mfma_f32_16x16x32_bf16(kB1, qf1, sB0, 0, 0, 0);
    sB1 = __builtin_amdgcn_mfma_f32_16x16x32_bf16(kB2, qf0, sB1, 0, 0, 0);
    sB1 = __builtin_amdgcn_mfma_f32_16x16x32_bf16(kB3, qf1, sB1, 0, 0, 0);

    const bf16x8 paA = __builtin_bit_cast(bf16x8, mask_exp(kt, sA0, sA1));
    const bf16x8 paB = __builtin_bit_cast(bf16x8, mask_exp(kt + 32, sB0, sB1));

    o_acc[0] = __builtin_amdgcn_mfma_f32_16x16x32_bf16(paA, vA0, o_acc[0], 0, 0, 0);
    o_acc[1] = __builtin_amdgcn_mfma_f32_16x16x32_bf16(paA, vA1, o_acc[1], 0, 0, 0);
    o_acc[2] = __builtin_amdgcn_mfma_f32_16x16x32_bf16(paA, vA2, o_acc[2], 0, 0, 0);
    o_acc[3] = __builtin_amdgcn_mfma_f32_16x16x32_bf16(paA, vA3, o_acc[3], 0, 0, 0);
    o_acc[0] = __builtin_amdgcn_mfma_f32_16x16x32_bf16(paB, vB0, o_acc[0], 0, 0, 0);
    o_acc[1] = __builtin_amdgcn_mfma_f32_16x16x32_bf16(paB, vB1, o_acc[1], 0, 0, 0);
    o_acc[2] = __builtin_amdgcn_mfma_f32_16x16x32_bf16(paB, vB2, o_acc[2], 0, 0, 0);
    o_acc[3] = __builtin_amdgcn_mfma_f32_16x16x32_bf16(paB, vB3, o_acc[3], 0, 0, 0);
  }

  // psum: partial row-sum for q = q_abs; 4 lgrp copies at lanes lrow+16g.
  psum += __shfl_xor(psum, 16);
  psum += __shfl_xor(psum, 32);

  // Redistribute: lane needs row sums for q rows lgrp*4+r (r=0..3).
  float psr[4];
#pragma unroll
  for (int r = 0; r < 4; ++r) psr[r] = __shfl(psum, lgrp * 4 + r, 64);
#pragma unroll
  for (int g = 0; g < 4; ++g)
#pragma unroll
    for (int r = 0; r < 4; ++r) {
      const int row = qw + lgrp * 4 + r;
      out[(size_t)row * DIM + h * HD + g * 16 + lrow] = o_acc[g][r] / psr[r];
    }
}

extern "C" void kernel_launch(void* const* d_in, const int* in_sizes, int n_in,
                              void* d_out, int out_size, void* d_ws, size_t ws_size,
                              hipStream_t stream) {
  const float* hsrc  = (const float*)d_in[0];
  const float* amask = (const float*)d_in[1];
  const float* Wq = (const float*)d_in[3];
  const float* bq = (const float*)d_in[4];
  const float* Wk = (const float*)d_in[5];
  const float* bk = (const float*)d_in[6];
  const float* Wv = (const float*)d_in[7];
  const float* bv = (const float*)d_in[8];
  float* out = (float*)d_out;
  char* ws = (char*)d_ws;
  const size_t MB = 1024 * 1024;
  u16*   Hb      = (u16*)(ws);                 // 8 MB: hidden bf16 [4096][1024]
  u16*   Wcat    = (u16*)(ws + 8 * MB);        // 6 MB: [3072][1024] bf16 (Wq|Wk|Wv)
  float* auxbuf  = (float*)(ws + 14 * MB);     // 28 KB: bias[3072] | fm[4096]
  u16*   Qh      = (u16*)(ws + 15 * MB);       // 8 MB: [NH][S][64] (pre-scaled by 0.125/ln2)
  u16*   Kh      = (u16*)(ws + 23 * MB);       // 8 MB: [NH][S][64]
  u16*   Vtile   = (u16*)(ws + 31 * MB);       // 8 MB: [NH][S/32][64][32] sigma-permuted

  cast4<<<4096, 256, 0, stream>>>(hsrc, Hb, SEQ * DIM);
  cast_w3<<<3072, 256, 0, stream>>>(Wq, Wk, Wv, Wcat);
  pack_aux<<<28, 256, 0, stream>>>(bq, bk, bv, amask, auxbuf);

  dim3 gq(3 * DIM / 256, SEQ / 256);  // (12, 16)
  gemm_qkv<<<gq, 512, 0, stream>>>(Hb, Wcat, auxbuf, Qh, Kh, Vtile);

  dim3 ga(SEQ / 64, NH);              // (64, 16) -> 1024 blocks, 4 independent waves each
  lf_attn<<<ga, 256, 0, stream>>>(Qh, Kh, Vtile, auxbuf + 3072, out);
}

// Round 11
// 76.167 us; speedup vs baseline: 1.3989x; 1.3989x over previous
//
#include <hip/hip_runtime.h>
#include <hip/hip_bf16.h>

typedef unsigned short u16;
typedef __attribute__((ext_vector_type(8))) __bf16 bf16x8;
typedef __attribute__((ext_vector_type(8))) unsigned short u16x8;
typedef __attribute__((ext_vector_type(4))) float f32x4;
typedef __attribute__((ext_vector_type(4))) unsigned short u16x4;

#define SEQ 4096
#define DIM 1024
#define NH 16
#define HD 64
#define WIN 256
#define NT32 (SEQ / 32)
#define NKT 32   // K-tiles of 32 in K=1024 (projection GEMM)
#define BQ 128   // q-rows per attention block

__device__ inline u16 f2bf(float f) {
  __hip_bfloat16 h = __float2bfloat16(f);
  return __builtin_bit_cast(u16, h);
}

__device__ inline void gload_lds16(const void* g, void* l) {
  auto gp = reinterpret_cast<__attribute__((address_space(1))) unsigned int*>(
      reinterpret_cast<unsigned long long>(g));
  auto lp = reinterpret_cast<__attribute__((address_space(3))) unsigned int*>(
      reinterpret_cast<unsigned long long>(l));
  __builtin_amdgcn_global_load_lds(gp, lp, 16, 0, 0);
}

__global__ __launch_bounds__(256) void cast4(const float* __restrict__ in,
                                             u16* __restrict__ out, int n) {
  int i = (blockIdx.x * 256 + threadIdx.x) * 4;
  if (i >= n) return;
  const float4 v = *reinterpret_cast<const float4*>(in + i);
  u16x4 r;
  r.x = f2bf(v.x); r.y = f2bf(v.y); r.z = f2bf(v.z); r.w = f2bf(v.w);
  *reinterpret_cast<u16x4*>(out + i) = r;
}

// Fused cast of the 3 weight matrices into Wcat.
__global__ __launch_bounds__(256) void cast_w3(const float* __restrict__ w0, const float* __restrict__ w1,
                                               const float* __restrict__ w2, u16* __restrict__ out) {
  int i = (blockIdx.x * 256 + threadIdx.x) * 4;
  const int seg = i >> 20;                 // 0,1,2
  const int loc = i & ((1 << 20) - 1);
  const float* src = (seg == 0) ? w0 : (seg == 1) ? w1 : w2;
  const float4 v = *reinterpret_cast<const float4*>(src + loc);
  u16x4 r;
  r.x = f2bf(v.x); r.y = f2bf(v.y); r.z = f2bf(v.z); r.w = f2bf(v.w);
  *reinterpret_cast<u16x4*>(out + i) = r;
}

// Pack 3 bias vectors (DIM each) + precomputed mask-add fm[SEQ] (exp2 domain).
__global__ __launch_bounds__(256) void pack_aux(const float* __restrict__ b0, const float* __restrict__ b1,
                                                const float* __restrict__ b2, const float* __restrict__ amask,
                                                float* __restrict__ out) {
  int i = blockIdx.x * 256 + threadIdx.x;  // 0..7167
  if (i < 3072) {
    const int seg = i >> 10, loc = i & 1023;
    out[i] = (seg == 0) ? b0[loc] : (seg == 1) ? b1[loc] : b2[loc];
  } else {
    const int j = i - 3072;
    out[i] = (amask[j] != 0.f) ? -14426.95f : 0.f;   // -10000/ln2
  }
}

// Stage one 256x32 A-panel tile + 256x32 B-panel tile into LDS slot.
__device__ __forceinline__ void stage_tile(const u16* __restrict__ A, const u16* __restrict__ B,
                                           int bm, int bn, u16* sa, u16* sb, int kt, int tid) {
  const int k0 = kt * 32;
#pragma unroll
  for (int l = 0; l < 2; ++l) {
    const int li = l * 512 + tid;         // 1024 chunks of 16B per matrix
    const int r = li >> 2, c = (li & 3) * 8;
    gload_lds16(A + (size_t)(bm + r) * DIM + k0 + c, sa + li * 8);
    gload_lds16(B + (size_t)(bn + r) * DIM + k0 + c, sb + li * 8);
  }
}

// Fused QKV projection, tri-buffered counted-vmcnt pipeline (T3/T4).
// Cols 0-1023    -> Qh [NH][S][64]  (x 0.125/ln2, exp2 trick)
// Cols 1024-2047 -> Kh [NH][S][64]
// Cols 2048-3071 -> Vtile [NH][S/32][64][32], key order sigma-PERMUTED within each 32-tile
//                   to match the zero-shuffle PV fragment in lf_attn.
__global__ __launch_bounds__(512, 2) void gemm_qkv(const u16* __restrict__ A, const u16* __restrict__ B,
                                                   const float* __restrict__ bias,
                                                   u16* __restrict__ Qh, u16* __restrict__ Kh,
                                                   u16* __restrict__ Vtile) {
  __shared__ __align__(16) u16 SA[3][256 * 32];
  __shared__ __align__(16) u16 SB[3][256 * 32];
  const int nwgx = gridDim.x;                        // 12
  const int orig = blockIdx.y * nwgx + blockIdx.x;   // 0..191
  const int cpx = (nwgx * gridDim.y) >> 3;           // 24
  const int wgid = (orig & 7) * cpx + (orig >> 3);   // bijective (192%8==0)
  const int bm = (wgid / nwgx) * 256, bn = (wgid % nwgx) * 256;
  const int tid = threadIdx.x;
  const int lane = tid & 63, wid = tid >> 6;
  const int lrow = lane & 15, lgrp = lane >> 4;
  const int wr = (wid >> 2) * 128, wc = (wid & 3) * 64;

  f32x4 acc[8][4];
  const f32x4 zero = {0.f, 0.f, 0.f, 0.f};
#pragma unroll
  for (int m = 0; m < 8; ++m)
#pragma unroll
    for (int n = 0; n < 4; ++n) acc[m][n] = zero;

  stage_tile(A, B, bm, bn, SA[0], SB[0], 0, tid);
  stage_tile(A, B, bm, bn, SA[1], SB[1], 1, tid);
  asm volatile("s_waitcnt vmcnt(4)" ::: "memory");   // tile0 landed (tile1 may fly)
  asm volatile("s_barrier" ::: "memory");

  for (int t = 0; t < NKT; ++t) {
    const int s = t % 3;
    if (t + 2 < NKT) stage_tile(A, B, bm, bn, SA[(t + 2) % 3], SB[(t + 2) % 3], t + 2, tid);
    bf16x8 af[8], bfr[4];
#pragma unroll
    for (int m = 0; m < 8; ++m)
      af[m] = *reinterpret_cast<const bf16x8*>(&SA[s][(wr + m * 16 + lrow) * 32 + lgrp * 8]);
#pragma unroll
    for (int n = 0; n < 4; ++n)
      bfr[n] = *reinterpret_cast<const bf16x8*>(&SB[s][(wc + n * 16 + lrow) * 32 + lgrp * 8]);
    __builtin_amdgcn_s_setprio(1);
#pragma unroll
    for (int m = 0; m < 8; ++m)
#pragma unroll
      for (int n = 0; n < 4; ++n)
        acc[m][n] = __builtin_amdgcn_mfma_f32_16x16x32_bf16(af[m], bfr[n], acc[m][n], 0, 0, 0);
    __builtin_amdgcn_s_setprio(0);
    if (t + 2 < NKT) { asm volatile("s_waitcnt vmcnt(4)" ::: "memory"); }
    else if (t + 1 < NKT) { asm volatile("s_waitcnt vmcnt(0)" ::: "memory"); }
    asm volatile("s_barrier" ::: "memory");
  }

#pragma unroll
  for (int m = 0; m < 8; ++m)
#pragma unroll
    for (int n = 0; n < 4; ++n) {
      const int row0 = bm + wr + m * 16 + lgrp * 4;
      const int colg = bn + wc + n * 16 + lrow;
      const float b = bias[colg];
      if (bn < 2048) {
        u16* dst = (bn < 1024) ? Qh : Kh;
        const float sc = (bn < 1024) ? 0.18033688f : 1.0f;  // 0.125/ln2 (exp2 trick)
        const int hh = (colg & 1023) >> 6;
        const int dd = colg & 63;
#pragma unroll
        for (int r = 0; r < 4; ++r)
          dst[((size_t)hh * SEQ + row0 + r) * HD + dd] = f2bf((acc[m][n][r] + b) * sc);
      } else {
        const int dv = colg - 2048;
        const int hh = dv >> 6, dd = dv & 63;
        const int k5 = row0 & 31;            // 4-aligned key offset within 32-tile
        const int pos = (k5 < 16) ? ((k5 >> 2) * 8) : (((k5 - 16) >> 2) * 8 + 4);
        u16x4 pk;
#pragma unroll
        for (int r = 0; r < 4; ++r) pk[r] = f2bf(acc[m][n][r] + b);
        u16* vt = Vtile + ((((size_t)hh * NT32 + (row0 >> 5)) * HD + dd) << 5) + pos;
        *reinterpret_cast<u16x4*>(vt) = pk;
      }
    }
}

// Banded flash attention. Block = 8 waves x 16 q-rows = 128 rows; the block's
// UNION key range is staged tile-by-tile (K 4KB + V 4KB) into tri-buffered LDS
// via global_load_lds (1 instr/thread/tile) with counted vmcnt. K/V traffic is
// loaded ONCE per block instead of once per wave (~7x L2 traffic cut).
// Swapped QK^T -> P lane-local for PV (zero shuffles). XOR-swizzled LDS
// (pre-swizzled SOURCE + swizzled ds_read; LDS dest stays linear - rule 21).
__global__ __launch_bounds__(512) void lf_attn(const u16* __restrict__ Qh, const u16* __restrict__ Kh,
                                               const u16* __restrict__ Vtile, const float* __restrict__ fm,
                                               float* __restrict__ out) {
  const int nwgx = gridDim.x;                       // 32
  const int nwg = nwgx * gridDim.y;                 // 512
  const int orig = blockIdx.y * nwgx + blockIdx.x;
  const int cpx = nwg >> 3;                         // 64
  const int wgid = (orig & 7) * cpx + (orig >> 3);  // bijective (512%8==0)
  const int h = wgid / nwgx;
  const int q0 = (wgid % nwgx) * BQ;
  const int tid = threadIdx.x;
  const int wid = tid >> 6, lane = tid & 63;
  const int lrow = lane & 15, lgrp = lane >> 4;
  const int qw = q0 + wid * 16;                     // this wave's 16 q-rows

  __shared__ __align__(16) u16 KL[3][32 * HD];      // 3 x 4KB, rows 128B
  __shared__ __align__(16) u16 VL[3][HD * 32];      // 3 x 4KB, rows 64B (sigma-permuted keys)

  bf16x8 qf0, qf1;
  {
    const u16* qbase = Qh + ((size_t)h * SEQ + qw + lrow) * HD + lgrp * 8;
    qf0 = *reinterpret_cast<const bf16x8*>(qbase);
    qf1 = *reinterpret_cast<const bf16x8*>(qbase + 32);
  }
  const f32x4 zero = {0.f, 0.f, 0.f, 0.f};
  f32x4 o_acc[4];
  float psum = 0.f;
#pragma unroll
  for (int g = 0; g < 4; ++g) o_acc[g] = zero;

  // Block-level union key range (all waves iterate it together).
  int kstart = q0 - WIN; if (kstart < 0) kstart = 0; kstart &= ~31;
  int kend = q0 + BQ - 1 + WIN + 1; if (kend > SEQ) kend = SEQ;   // multiple of 32
  const int NTT = (kend - kstart) >> 5;

  const int q_abs = qw + lrow;  // this lane's q row (swapped layout)

  // Stage tile t into LDS buffer buf. Source address pre-swizzled so that the
  // linear gload_lds dest yields XOR-swizzled LDS (K: slot^=(row&7), V: slot^=(row&3)).
  auto stage = [&](int t, int buf) {
    const int kt = kstart + t * 32;
    if (tid < 256) {
      const int row = tid >> 3, slot = tid & 7;     // K: 32 rows x 8 slots of 16B
      const u16* src = Kh + ((size_t)h * SEQ + kt + row) * HD + ((slot ^ (row & 7)) * 8);
      gload_lds16(src, &KL[buf][tid * 8]);
    } else {
      const int c = tid - 256;
      const int row = c >> 2, slot = c & 3;         // V: 64 rows x 4 slots of 16B
      const u16* src = Vtile + ((size_t)h * NT32 + (kt >> 5)) * (HD * 32) + row * 32 + ((slot ^ (row & 3)) * 8);
      gload_lds16(src, &VL[buf][c * 8]);
    }
  };

  stage(0, 0);
  stage(1, 1);
  asm volatile("s_waitcnt vmcnt(1)" ::: "memory");   // tile0 landed (tile1 may fly)
  asm volatile("s_barrier" ::: "memory");

  for (int t = 0; t < NTT; ++t) {
    const int s = t % 3;
    if (t + 2 < NTT) stage(t + 2, (t + 2) % 3);
    const int kt = kstart + t * 32;
    // Wave-uniform: does this tile intersect this wave's band at all?
    const bool active = (kt + 31 >= qw - WIN) && (kt <= qw + 15 + WIN);
    if (active) {
      const int xk = (lrow & 7) * 8;   // K swizzle (element units)
      const int xv = (lrow & 3) * 8;   // V swizzle
      const u16* KB = &KL[s][0];
      const u16* VB = &VL[s][0];
      const bf16x8 kf0 = *reinterpret_cast<const bf16x8*>(KB + lrow * 64        + (((lgrp)     * 8) ^ xk));
      const bf16x8 kf1 = *reinterpret_cast<const bf16x8*>(KB + lrow * 64        + (((lgrp + 4) * 8) ^ xk));
      const bf16x8 kf2 = *reinterpret_cast<const bf16x8*>(KB + (16 + lrow) * 64 + (((lgrp)     * 8) ^ xk));
      const bf16x8 kf3 = *reinterpret_cast<const bf16x8*>(KB + (16 + lrow) * 64 + (((lgrp + 4) * 8) ^ xk));
      const bf16x8 vf0 = *reinterpret_cast<const bf16x8*>(VB + lrow * 32        + ((lgrp * 8) ^ xv));
      const bf16x8 vf1 = *reinterpret_cast<const bf16x8*>(VB + (16 + lrow) * 32 + ((lgrp * 8) ^ xv));
      const bf16x8 vf2 = *reinterpret_cast<const bf16x8*>(VB + (32 + lrow) * 32 + ((lgrp * 8) ^ xv));
      const bf16x8 vf3 = *reinterpret_cast<const bf16x8*>(VB + (48 + lrow) * 32 + ((lgrp * 8) ^ xv));

      // Swapped score MFMAs: s0[r] = S[key=kt+lgrp*4+r][q=q_abs], s1: +16 keys.
      f32x4 s0 = zero, s1 = zero;
      s0 = __builtin_amdgcn_mfma_f32_16x16x32_bf16(kf0, qf0, s0, 0, 0, 0);
      s0 = __builtin_amdgcn_mfma_f32_16x16x32_bf16(kf1, qf1, s0, 0, 0, 0);
      s1 = __builtin_amdgcn_mfma_f32_16x16x32_bf16(kf2, qf0, s1, 0, 0, 0);
      s1 = __builtin_amdgcn_mfma_f32_16x16x32_bf16(kf3, qf1, s1, 0, 0, 0);

      const float4 f0 = *reinterpret_cast<const float4*>(fm + kt + lgrp * 4);
      const float4 f1 = *reinterpret_cast<const float4*>(fm + kt + 16 + lgrp * 4);
      const float f0v[4] = {f0.x, f0.y, f0.z, f0.w};
      const float f1v[4] = {f1.x, f1.y, f1.z, f1.w};

      u16x8 pu;
      if (kt >= qw - 241 && kt <= qw + 225) {
#pragma unroll
        for (int r = 0; r < 4; ++r) {
          const float e0 = __builtin_amdgcn_exp2f(s0[r] + f0v[r]);
          const float e1 = __builtin_amdgcn_exp2f(s1[r] + f1v[r]);
          psum += e0 + e1;
          pu[r] = f2bf(e0);
          pu[4 + r] = f2bf(e1);
        }
      } else {
#pragma unroll
        for (int r = 0; r < 4; ++r) {
          const int key0 = kt + lgrp * 4 + r;
          const int d0 = key0 - q_abs + WIN;   // valid iff 0 <= d0 <= 2*WIN
          const float e0 = ((unsigned)d0 <= 2u * WIN) ? __builtin_amdgcn_exp2f(s0[r] + f0v[r]) : 0.f;
          const float e1 = ((unsigned)(d0 + 16) <= 2u * WIN) ? __builtin_amdgcn_exp2f(s1[r] + f1v[r]) : 0.f;
          psum += e0 + e1;
          pu[r] = f2bf(e0);
          pu[4 + r] = f2bf(e1);
        }
      }
      const bf16x8 pa = __builtin_bit_cast(bf16x8, pu);
      o_acc[0] = __builtin_amdgcn_mfma_f32_16x16x32_bf16(pa, vf0, o_acc[0], 0, 0, 0);
      o_acc[1] = __builtin_amdgcn_mfma_f32_16x16x32_bf16(pa, vf1, o_acc[1], 0, 0, 0);
      o_acc[2] = __builtin_amdgcn_mfma_f32_16x16x32_bf16(pa, vf2, o_acc[2], 0, 0, 0);
      o_acc[3] = __builtin_amdgcn_mfma_f32_16x16x32_bf16(pa, vf3, o_acc[3], 0, 0, 0);
    }
    if (t + 2 < NTT) { asm volatile("s_waitcnt vmcnt(1)" ::: "memory"); }
    else if (t + 1 < NTT) { asm volatile("s_waitcnt vmcnt(0)" ::: "memory"); }
    asm volatile("s_barrier" ::: "memory");
  }

  // psum: partial row-sum for q = q_abs; 4 lgrp copies at lanes lrow+16g.
  psum += __shfl_xor(psum, 16);
  psum += __shfl_xor(psum, 32);

  // Redistribute: lane needs row sums for q rows lgrp*4+r (r=0..3).
  float psr[4];
#pragma unroll
  for (int r = 0; r < 4; ++r) psr[r] = __shfl(psum, lgrp * 4 + r, 64);
#pragma unroll
  for (int g = 0; g < 4; ++g)
#pragma unroll
    for (int r = 0; r < 4; ++r) {
      const int row = qw + lgrp * 4 + r;
      out[(size_t)row * DIM + h * HD + g * 16 + lrow] = o_acc[g][r] / psr[r];
    }
}

extern "C" void kernel_launch(void* const* d_in, const int* in_sizes, int n_in,
                              void* d_out, int out_size, void* d_ws, size_t ws_size,
                              hipStream_t stream) {
  const float* hsrc  = (const float*)d_in[0];
  const float* amask = (const float*)d_in[1];
  const float* Wq = (const float*)d_in[3];
  const float* bq = (const float*)d_in[4];
  const float* Wk = (const float*)d_in[5];
  const float* bk = (const float*)d_in[6];
  const float* Wv = (const float*)d_in[7];
  const float* bv = (const float*)d_in[8];
  float* out = (float*)d_out;
  char* ws = (char*)d_ws;
  const size_t MB = 1024 * 1024;
  u16*   Hb      = (u16*)(ws);                 // 8 MB: hidden bf16 [4096][1024]
  u16*   Wcat    = (u16*)(ws + 8 * MB);        // 6 MB: [3072][1024] bf16 (Wq|Wk|Wv)
  float* auxbuf  = (float*)(ws + 14 * MB);     // 28 KB: bias[3072] | fm[4096]
  u16*   Qh      = (u16*)(ws + 15 * MB);       // 8 MB: [NH][S][64] (pre-scaled by 0.125/ln2)
  u16*   Kh      = (u16*)(ws + 23 * MB);       // 8 MB: [NH][S][64]
  u16*   Vtile   = (u16*)(ws + 31 * MB);       // 8 MB: [NH][S/32][64][32] sigma-permuted

  cast4<<<4096, 256, 0, stream>>>(hsrc, Hb, SEQ * DIM);
  cast_w3<<<3072, 256, 0, stream>>>(Wq, Wk, Wv, Wcat);
  pack_aux<<<28, 256, 0, stream>>>(bq, bk, bv, amask, auxbuf);

  dim3 gq(3 * DIM / 256, SEQ / 256);  // (12, 16)
  gemm_qkv<<<gq, 512, 0, stream>>>(Hb, Wcat, auxbuf, Qh, Kh, Vtile);

  dim3 ga(SEQ / BQ, NH);              // (32, 16) -> 512 blocks x 8 waves
  lf_attn<<<ga, 512, 0, stream>>>(Qh, Kh, Vtile, auxbuf + 3072, out);
}

// Round 12
// 72.465 us; speedup vs baseline: 1.4703x; 1.0511x over previous
//
#include <hip/hip_runtime.h>
#include <hip/hip_bf16.h>

typedef unsigned short u16;
typedef __attribute__((ext_vector_type(8))) __bf16 bf16x8;
typedef __attribute__((ext_vector_type(8))) unsigned short u16x8;
typedef __attribute__((ext_vector_type(4))) float f32x4;
typedef __attribute__((ext_vector_type(4))) unsigned short u16x4;

#define SEQ 4096
#define DIM 1024
#define NH 16
#define HD 64
#define WIN 256
#define NT32 (SEQ / 32)
#define NKT 32   // K-tiles of 32 in K=1024 (projection GEMM)
#define BQ 128   // q-rows per attention block

__device__ inline u16 f2bf(float f) {
  __hip_bfloat16 h = __float2bfloat16(f);
  return __builtin_bit_cast(u16, h);
}

__device__ inline void gload_lds16(const void* g, void* l) {
  auto gp = reinterpret_cast<__attribute__((address_space(1))) unsigned int*>(
      reinterpret_cast<unsigned long long>(g));
  auto lp = reinterpret_cast<__attribute__((address_space(3))) unsigned int*>(
      reinterpret_cast<unsigned long long>(l));
  __builtin_amdgcn_global_load_lds(gp, lp, 16, 0, 0);
}

// Fused cast: hidden (4M elems) then Wq|Wk|Wv (3x1M) into bf16.
__global__ __launch_bounds__(256) void cast_all(const float* __restrict__ hsrc,
                                                const float* __restrict__ w0, const float* __restrict__ w1,
                                                const float* __restrict__ w2,
                                                u16* __restrict__ Hb, u16* __restrict__ Wcat) {
  int i = (blockIdx.x * 256 + threadIdx.x) * 4;
  const float* src;
  u16* dst;
  if (i < (1 << 22)) { src = hsrc + i; dst = Hb + i; }
  else {
    int j = i - (1 << 22);
    const int seg = j >> 20, loc = j & ((1 << 20) - 1);
    src = ((seg == 0) ? w0 : (seg == 1) ? w1 : w2) + loc;
    dst = Wcat + j;
  }
  const float4 v = *reinterpret_cast<const float4*>(src);
  u16x4 r;
  r.x = f2bf(v.x); r.y = f2bf(v.y); r.z = f2bf(v.z); r.w = f2bf(v.w);
  *reinterpret_cast<u16x4*>(dst) = r;
}

// Pack 3 bias vectors (DIM each) + precomputed mask-add fm[SEQ] (exp2 domain).
__global__ __launch_bounds__(256) void pack_aux(const float* __restrict__ b0, const float* __restrict__ b1,
                                                const float* __restrict__ b2, const float* __restrict__ amask,
                                                float* __restrict__ out) {
  int i = blockIdx.x * 256 + threadIdx.x;  // 0..7167
  if (i < 3072) {
    const int seg = i >> 10, loc = i & 1023;
    out[i] = (seg == 0) ? b0[loc] : (seg == 1) ? b1[loc] : b2[loc];
  } else {
    const int j = i - 3072;
    out[i] = (amask[j] != 0.f) ? -14426.95f : 0.f;   // -10000/ln2
  }
}

// ---- GEMM: 128x128 tile, BK=32, 4 waves, tri-buffered counted-vmcnt,
// ---- both-sides XOR-swizzled LDS (linear dest, pre-swizzled source, swizzled read).
// LDS layout per tile (128 rows x 32 cols bf16): 16B unit u = sr*8 + half*4 + sp
// holds global (row = sr*2+half, slot = sp ^ (sr&3)), slot = 8-elem k-chunk.
// Read addr for (row, lgrp): elem = (row>>1)*64 + (row&1)*32 + (lgrp^((row>>1)&3))*8
// -> wave's 64 lanes spread evenly over all 8 bank groups (2 lanes/bank = free).
__device__ __forceinline__ void stage_tile128(const u16* __restrict__ A, const u16* __restrict__ B,
                                              int bm, int bn, u16* sa, u16* sb, int kt, int tid) {
  const int k0 = kt * 32;
#pragma unroll
  for (int l = 0; l < 2; ++l) {
    const int u = l * 256 + tid;               // 512 units of 16B per matrix
    const int sr = u >> 3, half = (u >> 2) & 1, sp = u & 3;
    const int row = sr * 2 + half;
    const int slot = sp ^ (sr & 3);
    gload_lds16(A + (size_t)(bm + row) * DIM + k0 + slot * 8, sa + u * 8);
    gload_lds16(B + (size_t)(bn + row) * DIM + k0 + slot * 8, sb + u * 8);
  }
}

// Fused QKV projection.
// Cols 0-1023    -> Qh [NH][S][64]  (x 0.125/ln2, exp2 trick)
// Cols 1024-2047 -> Kh [NH][S][64]
// Cols 2048-3071 -> Vtile [NH][S/32][64][32], sigma-permuted keys (zero-shuffle PV).
__global__ __launch_bounds__(256, 3) void gemm_qkv(const u16* __restrict__ A, const u16* __restrict__ B,
                                                   const float* __restrict__ bias,
                                                   u16* __restrict__ Qh, u16* __restrict__ Kh,
                                                   u16* __restrict__ Vtile) {
  __shared__ __align__(16) u16 SA[3][128 * 32];
  __shared__ __align__(16) u16 SB[3][128 * 32];
  const int nwgx = gridDim.x;                        // 24
  const int orig = blockIdx.y * nwgx + blockIdx.x;   // 0..767
  const int cpx = (nwgx * gridDim.y) >> 3;           // 96
  const int wgid = (orig & 7) * cpx + (orig >> 3);   // bijective (768%8==0)
  const int bm = (wgid / nwgx) * 128, bn = (wgid % nwgx) * 128;
  const int tid = threadIdx.x;
  const int lane = tid & 63, wid = tid >> 6;
  const int lrow = lane & 15, lgrp = lane >> 4;
  const int wr = (wid >> 1) * 64, wc = (wid & 1) * 64;

  f32x4 acc[4][4];
  const f32x4 zero = {0.f, 0.f, 0.f, 0.f};
#pragma unroll
  for (int m = 0; m < 4; ++m)
#pragma unroll
    for (int n = 0; n < 4; ++n) acc[m][n] = zero;

  stage_tile128(A, B, bm, bn, SA[0], SB[0], 0, tid);
  stage_tile128(A, B, bm, bn, SA[1], SB[1], 1, tid);
  asm volatile("s_waitcnt vmcnt(4)" ::: "memory");   // tile0 landed (tile1 may fly)
  asm volatile("s_barrier" ::: "memory");

  for (int t = 0; t < NKT; ++t) {
    const int s = t % 3;
    if (t + 2 < NKT) stage_tile128(A, B, bm, bn, SA[(t + 2) % 3], SB[(t + 2) % 3], t + 2, tid);
    bf16x8 af[4], bfr[4];
#pragma unroll
    for (int m = 0; m < 4; ++m) {
      const int row = wr + m * 16 + lrow;
      af[m] = *reinterpret_cast<const bf16x8*>(
          &SA[s][(row >> 1) * 64 + (row & 1) * 32 + ((lgrp ^ ((row >> 1) & 3)) * 8)]);
    }
#pragma unroll
    for (int n = 0; n < 4; ++n) {
      const int row = wc + n * 16 + lrow;
      bfr[n] = *reinterpret_cast<const bf16x8*>(
          &SB[s][(row >> 1) * 64 + (row & 1) * 32 + ((lgrp ^ ((row >> 1) & 3)) * 8)]);
    }
    __builtin_amdgcn_s_setprio(1);
#pragma unroll
    for (int m = 0; m < 4; ++m)
#pragma unroll
      for (int n = 0; n < 4; ++n)
        acc[m][n] = __builtin_amdgcn_mfma_f32_16x16x32_bf16(af[m], bfr[n], acc[m][n], 0, 0, 0);
    __builtin_amdgcn_s_setprio(0);
    if (t + 2 < NKT) { asm volatile("s_waitcnt vmcnt(4)" ::: "memory"); }
    else if (t + 1 < NKT) { asm volatile("s_waitcnt vmcnt(0)" ::: "memory"); }
    asm volatile("s_barrier" ::: "memory");
  }

#pragma unroll
  for (int m = 0; m < 4; ++m)
#pragma unroll
    for (int n = 0; n < 4; ++n) {
      const int row0 = bm + wr + m * 16 + lgrp * 4;
      const int colg = bn + wc + n * 16 + lrow;
      const float b = bias[colg];
      if (bn < 2048) {
        u16* dst = (bn < 1024) ? Qh : Kh;
        const float sc = (bn < 1024) ? 0.18033688f : 1.0f;  // 0.125/ln2 (exp2 trick)
        const int hh = (colg & 1023) >> 6;
        const int dd = colg & 63;
#pragma unroll
        for (int r = 0; r < 4; ++r)
          dst[((size_t)hh * SEQ + row0 + r) * HD + dd] = f2bf((acc[m][n][r] + b) * sc);
      } else {
        const int dv = colg - 2048;
        const int hh = dv >> 6, dd = dv & 63;
        const int k5 = row0 & 31;            // 4-aligned key offset within 32-tile
        const int pos = (k5 < 16) ? ((k5 >> 2) * 8) : (((k5 - 16) >> 2) * 8 + 4);
        u16x4 pk;
#pragma unroll
        for (int r = 0; r < 4; ++r) pk[r] = f2bf(acc[m][n][r] + b);
        u16* vt = Vtile + ((((size_t)hh * NT32 + (row0 >> 5)) * HD + dd) << 5) + pos;
        *reinterpret_cast<u16x4*>(vt) = pk;
      }
    }
}

// Banded flash attention (round-11 structure, unchanged): block = 8 waves x 16
// q-rows; union key range staged tile-by-tile into tri-buffered LDS via
// global_load_lds with counted vmcnt; swapped QK^T (P lane-local, zero shuffles);
// XOR-swizzled LDS via pre-swizzled source + swizzled ds_read.
__global__ __launch_bounds__(512) void lf_attn(const u16* __restrict__ Qh, const u16* __restrict__ Kh,
                                               const u16* __restrict__ Vtile, const float* __restrict__ fm,
                                               float* __restrict__ out) {
  const int nwgx = gridDim.x;                       // 32
  const int nwg = nwgx * gridDim.y;                 // 512
  const int orig = blockIdx.y * nwgx + blockIdx.x;
  const int cpx = nwg >> 3;                         // 64
  const int wgid = (orig & 7) * cpx + (orig >> 3);  // bijective (512%8==0)
  const int h = wgid / nwgx;
  const int q0 = (wgid % nwgx) * BQ;
  const int tid = threadIdx.x;
  const int wid = tid >> 6, lane = tid & 63;
  const int lrow = lane & 15, lgrp = lane >> 4;
  const int qw = q0 + wid * 16;                     // this wave's 16 q-rows

  __shared__ __align__(16) u16 KL[3][32 * HD];      // 3 x 4KB, rows 128B
  __shared__ __align__(16) u16 VL[3][HD * 32];      // 3 x 4KB, rows 64B (sigma-permuted keys)

  bf16x8 qf0, qf1;
  {
    const u16* qbase = Qh + ((size_t)h * SEQ + qw + lrow) * HD + lgrp * 8;
    qf0 = *reinterpret_cast<const bf16x8*>(qbase);
    qf1 = *reinterpret_cast<const bf16x8*>(qbase + 32);
  }
  const f32x4 zero = {0.f, 0.f, 0.f, 0.f};
  f32x4 o_acc[4];
  float psum = 0.f;
#pragma unroll
  for (int g = 0; g < 4; ++g) o_acc[g] = zero;

  // Block-level union key range (all waves iterate it together).
  int kstart = q0 - WIN; if (kstart < 0) kstart = 0; kstart &= ~31;
  int kend = q0 + BQ - 1 + WIN + 1; if (kend > SEQ) kend = SEQ;   // multiple of 32
  const int NTT = (kend - kstart) >> 5;

  const int q_abs = qw + lrow;  // this lane's q row (swapped layout)

  auto stage = [&](int t, int buf) {
    const int kt = kstart + t * 32;
    if (tid < 256) {
      const int row = tid >> 3, slot = tid & 7;     // K: 32 rows x 8 slots of 16B
      const u16* src = Kh + ((size_t)h * SEQ + kt + row) * HD + ((slot ^ (row & 7)) * 8);
      gload_lds16(src, &KL[buf][tid * 8]);
    } else {
      const int c = tid - 256;
      const int row = c >> 2, slot = c & 3;         // V: 64 rows x 4 slots of 16B
      const u16* src = Vtile + ((size_t)h * NT32 + (kt >> 5)) * (HD * 32) + row * 32 + ((slot ^ (row & 3)) * 8);
      gload_lds16(src, &VL[buf][c * 8]);
    }
  };

  stage(0, 0);
  stage(1, 1);
  asm volatile("s_waitcnt vmcnt(1)" ::: "memory");   // tile0 landed (tile1 may fly)
  asm volatile("s_barrier" ::: "memory");

  for (int t = 0; t < NTT; ++t) {
    const int s = t % 3;
    if (t + 2 < NTT) stage(t + 2, (t + 2) % 3);
    const int kt = kstart + t * 32;
    const bool active = (kt + 31 >= qw - WIN) && (kt <= qw + 15 + WIN);
    if (active) {
      const int xk = (lrow & 7) * 8;   // K swizzle (element units)
      const int xv = (lrow & 3) * 8;   // V swizzle
      const u16* KB = &KL[s][0];
      const u16* VB = &VL[s][0];
      const bf16x8 kf0 = *reinterpret_cast<const bf16x8*>(KB + lrow * 64        + (((lgrp)     * 8) ^ xk));
      const bf16x8 kf1 = *reinterpret_cast<const bf16x8*>(KB + lrow * 64        + (((lgrp + 4) * 8) ^ xk));
      const bf16x8 kf2 = *reinterpret_cast<const bf16x8*>(KB + (16 + lrow) * 64 + (((lgrp)     * 8) ^ xk));
      const bf16x8 kf3 = *reinterpret_cast<const bf16x8*>(KB + (16 + lrow) * 64 + (((lgrp + 4) * 8) ^ xk));
      const bf16x8 vf0 = *reinterpret_cast<const bf16x8*>(VB + lrow * 32        + ((lgrp * 8) ^ xv));
      const bf16x8 vf1 = *reinterpret_cast<const bf16x8*>(VB + (16 + lrow) * 32 + ((lgrp * 8) ^ xv));
      const bf16x8 vf2 = *reinterpret_cast<const bf16x8*>(VB + (32 + lrow) * 32 + ((lgrp * 8) ^ xv));
      const bf16x8 vf3 = *reinterpret_cast<const bf16x8*>(VB + (48 + lrow) * 32 + ((lgrp * 8) ^ xv));

      f32x4 s0 = zero, s1 = zero;
      s0 = __builtin_amdgcn_mfma_f32_16x16x32_bf16(kf0, qf0, s0, 0, 0, 0);
      s0 = __builtin_amdgcn_mfma_f32_16x16x32_bf16(kf1, qf1, s0, 0, 0, 0);
      s1 = __builtin_amdgcn_mfma_f32_16x16x32_bf16(kf2, qf0, s1, 0, 0, 0);
      s1 = __builtin_amdgcn_mfma_f32_16x16x32_bf16(kf3, qf1, s1, 0, 0, 0);

      const float4 f0 = *reinterpret_cast<const float4*>(fm + kt + lgrp * 4);
      const float4 f1 = *reinterpret_cast<const float4*>(fm + kt + 16 + lgrp * 4);
      const float f0v[4] = {f0.x, f0.y, f0.z, f0.w};
      const float f1v[4] = {f1.x, f1.y, f1.z, f1.w};

      u16x8 pu;
      if (kt >= qw - 241 && kt <= qw + 225) {
#pragma unroll
        for (int r = 0; r < 4; ++r) {
          const float e0 = __builtin_amdgcn_exp2f(s0[r] + f0v[r]);
          const float e1 = __builtin_amdgcn_exp2f(s1[r] + f1v[r]);
          psum += e0 + e1;
          pu[r] = f2bf(e0);
          pu[4 + r] = f2bf(e1);
        }
      } else {
#pragma unroll
        for (int r = 0; r < 4; ++r) {
          const int key0 = kt + lgrp * 4 + r;
          const int d0 = key0 - q_abs + WIN;   // valid iff 0 <= d0 <= 2*WIN
          const float e0 = ((unsigned)d0 <= 2u * WIN) ? __builtin_amdgcn_exp2f(s0[r] + f0v[r]) : 0.f;
          const float e1 = ((unsigned)(d0 + 16) <= 2u * WIN) ? __builtin_amdgcn_exp2f(s1[r] + f1v[r]) : 0.f;
          psum += e0 + e1;
          pu[r] = f2bf(e0);
          pu[4 + r] = f2bf(e1);
        }
      }
      const bf16x8 pa = __builtin_bit_cast(bf16x8, pu);
      o_acc[0] = __builtin_amdgcn_mfma_f32_16x16x32_bf16(pa, vf0, o_acc[0], 0, 0, 0);
      o_acc[1] = __builtin_amdgcn_mfma_f32_16x16x32_bf16(pa, vf1, o_acc[1], 0, 0, 0);
      o_acc[2] = __builtin_amdgcn_mfma_f32_16x16x32_bf16(pa, vf2, o_acc[2], 0, 0, 0);
      o_acc[3] = __builtin_amdgcn_mfma_f32_16x16x32_bf16(pa, vf3, o_acc[3], 0, 0, 0);
    }
    if (t + 2 < NTT) { asm volatile("s_waitcnt vmcnt(1)" ::: "memory"); }
    else if (t + 1 < NTT) { asm volatile("s_waitcnt vmcnt(0)" ::: "memory"); }
    asm volatile("s_barrier" ::: "memory");
  }

  psum += __shfl_xor(psum, 16);
  psum += __shfl_xor(psum, 32);

  float psr[4];
#pragma unroll
  for (int r = 0; r < 4; ++r) psr[r] = __shfl(psum, lgrp * 4 + r, 64);
#pragma unroll
  for (int g = 0; g < 4; ++g)
#pragma unroll
    for (int r = 0; r < 4; ++r) {
      const int row = qw + lgrp * 4 + r;
      out[(size_t)row * DIM + h * HD + g * 16 + lrow] = o_acc[g][r] / psr[r];
    }
}

extern "C" void kernel_launch(void* const* d_in, const int* in_sizes, int n_in,
                              void* d_out, int out_size, void* d_ws, size_t ws_size,
                              hipStream_t stream) {
  const float* hsrc  = (const float*)d_in[0];
  const float* amask = (const float*)d_in[1];
  const float* Wq = (const float*)d_in[3];
  const float* bq = (const float*)d_in[4];
  const float* Wk = (const float*)d_in[5];
  const float* bk = (const float*)d_in[6];
  const float* Wv = (const float*)d_in[7];
  const float* bv = (const float*)d_in[8];
  float* out = (float*)d_out;
  char* ws = (char*)d_ws;
  const size_t MB = 1024 * 1024;
  u16*   Hb      = (u16*)(ws);                 // 8 MB: hidden bf16 [4096][1024]
  u16*   Wcat    = (u16*)(ws + 8 * MB);        // 6 MB: [3072][1024] bf16 (Wq|Wk|Wv)
  float* auxbuf  = (float*)(ws + 14 * MB);     // 28 KB: bias[3072] | fm[4096]
  u16*   Qh      = (u16*)(ws + 15 * MB);       // 8 MB: [NH][S][64] (pre-scaled by 0.125/ln2)
  u16*   Kh      = (u16*)(ws + 23 * MB);       // 8 MB: [NH][S][64]
  u16*   Vtile   = (u16*)(ws + 31 * MB);       // 8 MB: [NH][S/32][64][32] sigma-permuted

  cast_all<<<7168, 256, 0, stream>>>(hsrc, Wq, Wk, Wv, Hb, Wcat);
  pack_aux<<<28, 256, 0, stream>>>(bq, bk, bv, amask, auxbuf);

  dim3 gq(3 * DIM / 128, SEQ / 128);  // (24, 32) = 768 blocks
  gemm_qkv<<<gq, 256, 0, stream>>>(Hb, Wcat, auxbuf, Qh, Kh, Vtile);

  dim3 ga(SEQ / BQ, NH);              // (32, 16) -> 512 blocks x 8 waves
  lf_attn<<<ga, 512, 0, stream>>>(Qh, Kh, Vtile, auxbuf + 3072, out);
}

// Round 13
// 68.234 us; speedup vs baseline: 1.5615x; 1.0620x over previous
//
#include <hip/hip_runtime.h>
#include <hip/hip_bf16.h>

typedef unsigned short u16;
typedef __attribute__((ext_vector_type(8))) __bf16 bf16x8;
typedef __attribute__((ext_vector_type(8))) unsigned short u16x8;
typedef __attribute__((ext_vector_type(4))) float f32x4;
typedef __attribute__((ext_vector_type(4))) unsigned short u16x4;

#define SEQ 4096
#define DIM 1024
#define NH 16
#define HD 64
#define WIN 256
#define NT32 (SEQ / 32)
#define NKT 32   // K-tiles of 32 in K=1024 (projection GEMM)
#define BQ 128   // q-rows per attention block

__device__ inline u16 f2bf(float f) {
  __hip_bfloat16 h = __float2bfloat16(f);
  return __builtin_bit_cast(u16, h);
}

__device__ inline void gload_lds16(const void* g, void* l) {
  auto gp = reinterpret_cast<__attribute__((address_space(1))) unsigned int*>(
      reinterpret_cast<unsigned long long>(g));
  auto lp = reinterpret_cast<__attribute__((address_space(3))) unsigned int*>(
      reinterpret_cast<unsigned long long>(l));
  __builtin_amdgcn_global_load_lds(gp, lp, 16, 0, 0);
}

// Fused cast (hidden + 3 weights -> bf16) + aux pack (bias cat + fm mask table).
__global__ __launch_bounds__(256) void cast_all(const float* __restrict__ hsrc,
                                                const float* __restrict__ w0, const float* __restrict__ w1,
                                                const float* __restrict__ w2,
                                                const float* __restrict__ b0, const float* __restrict__ b1,
                                                const float* __restrict__ b2, const float* __restrict__ amask,
                                                u16* __restrict__ Hb, u16* __restrict__ Wcat,
                                                float* __restrict__ aux) {
  const int bid = blockIdx.x;
  if (bid < 7168) {
    int i = (bid * 256 + threadIdx.x) * 4;
    const float* src;
    u16* dst;
    if (i < (1 << 22)) { src = hsrc + i; dst = Hb + i; }
    else {
      int j = i - (1 << 22);
      const int seg = j >> 20, loc = j & ((1 << 20) - 1);
      src = ((seg == 0) ? w0 : (seg == 1) ? w1 : w2) + loc;
      dst = Wcat + j;
    }
    const float4 v = *reinterpret_cast<const float4*>(src);
    u16x4 r;
    r.x = f2bf(v.x); r.y = f2bf(v.y); r.z = f2bf(v.z); r.w = f2bf(v.w);
    *reinterpret_cast<u16x4*>(dst) = r;
  } else {
    int i = (bid - 7168) * 256 + threadIdx.x;   // 0..7167
    if (i < 3072) {
      const int seg = i >> 10, loc = i & 1023;
      aux[i] = (seg == 0) ? b0[loc] : (seg == 1) ? b1[loc] : b2[loc];
    } else {
      const int j = i - 3072;
      aux[i] = (amask[j] != 0.f) ? -14426.95f : 0.f;   // -10000/ln2
    }
  }
}

// ---- GEMM: 256(M)x128(N) tile, BK=32, 4 waves (2Mx2N), per-wave 128x64 (8x4 acc).
// Tri-buffered counted-vmcnt pipeline; both-sides XOR-swizzled LDS (linear dest,
// pre-swizzled source, swizzled read): 16B unit u = sr*8 + half*4 + sp holds global
// (row = sr*2+half, slot = sp ^ (sr&3)); read elem = (row>>1)*64 + (row&1)*32 +
// (lgrp^((row>>1)&3))*8 -> 64 lanes spread 2/bank-group (free).
__device__ __forceinline__ void stage_tile(const u16* __restrict__ A, const u16* __restrict__ B,
                                           int bm, int bn, u16* sa, u16* sb, int kt, int tid) {
  const int k0 = kt * 32;
#pragma unroll
  for (int l = 0; l < 4; ++l) {                // A: 256x32 = 1024 units of 16B
    const int u = l * 256 + tid;
    const int sr = u >> 3, half = (u >> 2) & 1, sp = u & 3;
    const int row = sr * 2 + half;
    const int slot = sp ^ (sr & 3);
    gload_lds16(A + (size_t)(bm + row) * DIM + k0 + slot * 8, sa + u * 8);
  }
#pragma unroll
  for (int l = 0; l < 2; ++l) {                // B: 128x32 = 512 units of 16B
    const int u = l * 256 + tid;
    const int sr = u >> 3, half = (u >> 2) & 1, sp = u & 3;
    const int row = sr * 2 + half;
    const int slot = sp ^ (sr & 3);
    gload_lds16(B + (size_t)(bn + row) * DIM + k0 + slot * 8, sb + u * 8);
  }
}

// Fused QKV projection.
// Cols 0-1023    -> Qh [NH][S][64]  (x 0.125/ln2, exp2 trick)
// Cols 1024-2047 -> Kh [NH][S][64]
// Cols 2048-3071 -> Vtile [NH][S/32][64][32], sigma-permuted keys (zero-shuffle PV).
__global__ __launch_bounds__(256, 2) void gemm_qkv(const u16* __restrict__ A, const u16* __restrict__ B,
                                                   const float* __restrict__ bias,
                                                   u16* __restrict__ Qh, u16* __restrict__ Kh,
                                                   u16* __restrict__ Vtile) {
  __shared__ __align__(16) u16 SA[3][256 * 32];
  __shared__ __align__(16) u16 SB[3][128 * 32];
  const int nwgx = gridDim.x;                        // 24
  const int orig = blockIdx.y * nwgx + blockIdx.x;   // 0..383
  const int cpx = (nwgx * gridDim.y) >> 3;           // 48
  const int wgid = (orig & 7) * cpx + (orig >> 3);   // bijective (384%8==0)
  const int bm = (wgid / nwgx) * 256, bn = (wgid % nwgx) * 128;
  const int tid = threadIdx.x;
  const int lane = tid & 63, wid = tid >> 6;
  const int lrow = lane & 15, lgrp = lane >> 4;
  const int wr = (wid >> 1) * 128, wc = (wid & 1) * 64;

  f32x4 acc[8][4];
  const f32x4 zero = {0.f, 0.f, 0.f, 0.f};
#pragma unroll
  for (int m = 0; m < 8; ++m)
#pragma unroll
    for (int n = 0; n < 4; ++n) acc[m][n] = zero;

  stage_tile(A, B, bm, bn, SA[0], SB[0], 0, tid);
  stage_tile(A, B, bm, bn, SA[1], SB[1], 1, tid);
  asm volatile("s_waitcnt vmcnt(6)" ::: "memory");   // tile0 landed (tile1 may fly)
  asm volatile("s_barrier" ::: "memory");

  for (int t = 0; t < NKT; ++t) {
    const int s = t % 3;
    if (t + 2 < NKT) stage_tile(A, B, bm, bn, SA[(t + 2) % 3], SB[(t + 2) % 3], t + 2, tid);
    bf16x8 af[8], bfr[4];
#pragma unroll
    for (int m = 0; m < 8; ++m) {
      const int row = wr + m * 16 + lrow;
      af[m] = *reinterpret_cast<const bf16x8*>(
          &SA[s][(row >> 1) * 64 + (row & 1) * 32 + ((lgrp ^ ((row >> 1) & 3)) * 8)]);
    }
#pragma unroll
    for (int n = 0; n < 4; ++n) {
      const int row = wc + n * 16 + lrow;
      bfr[n] = *reinterpret_cast<const bf16x8*>(
          &SB[s][(row >> 1) * 64 + (row & 1) * 32 + ((lgrp ^ ((row >> 1) & 3)) * 8)]);
    }
    __builtin_amdgcn_s_setprio(1);
#pragma unroll
    for (int m = 0; m < 8; ++m)
#pragma unroll
      for (int n = 0; n < 4; ++n)
        acc[m][n] = __builtin_amdgcn_mfma_f32_16x16x32_bf16(af[m], bfr[n], acc[m][n], 0, 0, 0);
    __builtin_amdgcn_s_setprio(0);
    if (t + 2 < NKT) { asm volatile("s_waitcnt vmcnt(6)" ::: "memory"); }
    else if (t + 1 < NKT) { asm volatile("s_waitcnt vmcnt(0)" ::: "memory"); }
    asm volatile("s_barrier" ::: "memory");
  }

#pragma unroll
  for (int m = 0; m < 8; ++m)
#pragma unroll
    for (int n = 0; n < 4; ++n) {
      const int row0 = bm + wr + m * 16 + lgrp * 4;
      const int colg = bn + wc + n * 16 + lrow;
      const float b = bias[colg];
      if (bn < 2048) {
        u16* dst = (bn < 1024) ? Qh : Kh;
        const float sc = (bn < 1024) ? 0.18033688f : 1.0f;  // 0.125/ln2 (exp2 trick)
        const int hh = (colg & 1023) >> 6;
        const int dd = colg & 63;
#pragma unroll
        for (int r = 0; r < 4; ++r)
          dst[((size_t)hh * SEQ + row0 + r) * HD + dd] = f2bf((acc[m][n][r] + b) * sc);
      } else {
        const int dv = colg - 2048;
        const int hh = dv >> 6, dd = dv & 63;
        const int k5 = row0 & 31;            // 4-aligned key offset within 32-tile
        const int pos = (k5 < 16) ? ((k5 >> 2) * 8) : (((k5 - 16) >> 2) * 8 + 4);
        u16x4 pk;
#pragma unroll
        for (int r = 0; r < 4; ++r) pk[r] = f2bf(acc[m][n][r] + b);
        u16* vt = Vtile + ((((size_t)hh * NT32 + (row0 >> 5)) * HD + dd) << 5) + pos;
        *reinterpret_cast<u16x4*>(vt) = pk;
      }
    }
}

// Banded flash attention (round-11 structure, unchanged): block = 8 waves x 16
// q-rows; union key range staged tile-by-tile into tri-buffered LDS via
// global_load_lds with counted vmcnt; swapped QK^T (P lane-local, zero shuffles);
// XOR-swizzled LDS via pre-swizzled source + swizzled ds_read.
__global__ __launch_bounds__(512) void lf_attn(const u16* __restrict__ Qh, const u16* __restrict__ Kh,
                                               const u16* __restrict__ Vtile, const float* __restrict__ fm,
                                               float* __restrict__ out) {
  const int nwgx = gridDim.x;                       // 32
  const int nwg = nwgx * gridDim.y;                 // 512
  const int orig = blockIdx.y * nwgx + blockIdx.x;
  const int cpx = nwg >> 3;                         // 64
  const int wgid = (orig & 7) * cpx + (orig >> 3);  // bijective (512%8==0)
  const int h = wgid / nwgx;
  const int q0 = (wgid % nwgx) * BQ;
  const int tid = threadIdx.x;
  const int wid = tid >> 6, lane = tid & 63;
  const int lrow = lane & 15, lgrp = lane >> 4;
  const int qw = q0 + wid * 16;                     // this wave's 16 q-rows

  __shared__ __align__(16) u16 KL[3][32 * HD];      // 3 x 4KB, rows 128B
  __shared__ __align__(16) u16 VL[3][HD * 32];      // 3 x 4KB, rows 64B (sigma-permuted keys)

  bf16x8 qf0, qf1;
  {
    const u16* qbase = Qh + ((size_t)h * SEQ + qw + lrow) * HD + lgrp * 8;
    qf0 = *reinterpret_cast<const bf16x8*>(qbase);
    qf1 = *reinterpret_cast<const bf16x8*>(qbase + 32);
  }
  const f32x4 zero = {0.f, 0.f, 0.f, 0.f};
  f32x4 o_acc[4];
  float psum = 0.f;
#pragma unroll
  for (int g = 0; g < 4; ++g) o_acc[g] = zero;

  // Block-level union key range (all waves iterate it together).
  int kstart = q0 - WIN; if (kstart < 0) kstart = 0; kstart &= ~31;
  int kend = q0 + BQ - 1 + WIN + 1; if (kend > SEQ) kend = SEQ;   // multiple of 32
  const int NTT = (kend - kstart) >> 5;

  const int q_abs = qw + lrow;  // this lane's q row (swapped layout)

  auto stage = [&](int t, int buf) {
    const int kt = kstart + t * 32;
    if (tid < 256) {
      const int row = tid >> 3, slot = tid & 7;     // K: 32 rows x 8 slots of 16B
      const u16* src = Kh + ((size_t)h * SEQ + kt + row) * HD + ((slot ^ (row & 7)) * 8);
      gload_lds16(src, &KL[buf][tid * 8]);
    } else {
      const int c = tid - 256;
      const int row = c >> 2, slot = c & 3;         // V: 64 rows x 4 slots of 16B
      const u16* src = Vtile + ((size_t)h * NT32 + (kt >> 5)) * (HD * 32) + row * 32 + ((slot ^ (row & 3)) * 8);
      gload_lds16(src, &VL[buf][c * 8]);
    }
  };

  stage(0, 0);
  stage(1, 1);
  asm volatile("s_waitcnt vmcnt(1)" ::: "memory");   // tile0 landed (tile1 may fly)
  asm volatile("s_barrier" ::: "memory");

  for (int t = 0; t < NTT; ++t) {
    const int s = t % 3;
    if (t + 2 < NTT) stage(t + 2, (t + 2) % 3);
    const int kt = kstart + t * 32;
    const bool active = (kt + 31 >= qw - WIN) && (kt <= qw + 15 + WIN);
    if (active) {
      const int xk = (lrow & 7) * 8;   // K swizzle (element units)
      const int xv = (lrow & 3) * 8;   // V swizzle
      const u16* KB = &KL[s][0];
      const u16* VB = &VL[s][0];
      const bf16x8 kf0 = *reinterpret_cast<const bf16x8*>(KB + lrow * 64        + (((lgrp)     * 8) ^ xk));
      const bf16x8 kf1 = *reinterpret_cast<const bf16x8*>(KB + lrow * 64        + (((lgrp + 4) * 8) ^ xk));
      const bf16x8 kf2 = *reinterpret_cast<const bf16x8*>(KB + (16 + lrow) * 64 + (((lgrp)     * 8) ^ xk));
      const bf16x8 kf3 = *reinterpret_cast<const bf16x8*>(KB + (16 + lrow) * 64 + (((lgrp + 4) * 8) ^ xk));
      const bf16x8 vf0 = *reinterpret_cast<const bf16x8*>(VB + lrow * 32        + ((lgrp * 8) ^ xv));
      const bf16x8 vf1 = *reinterpret_cast<const bf16x8*>(VB + (16 + lrow) * 32 + ((lgrp * 8) ^ xv));
      const bf16x8 vf2 = *reinterpret_cast<const bf16x8*>(VB + (32 + lrow) * 32 + ((lgrp * 8) ^ xv));
      const bf16x8 vf3 = *reinterpret_cast<const bf16x8*>(VB + (48 + lrow) * 32 + ((lgrp * 8) ^ xv));

      f32x4 s0 = zero, s1 = zero;
      s0 = __builtin_amdgcn_mfma_f32_16x16x32_bf16(kf0, qf0, s0, 0, 0, 0);
      s0 = __builtin_amdgcn_mfma_f32_16x16x32_bf16(kf1, qf1, s0, 0, 0, 0);
      s1 = __builtin_amdgcn_mfma_f32_16x16x32_bf16(kf2, qf0, s1, 0, 0, 0);
      s1 = __builtin_amdgcn_mfma_f32_16x16x32_bf16(kf3, qf1, s1, 0, 0, 0);

      const float4 f0 = *reinterpret_cast<const float4*>(fm + kt + lgrp * 4);
      const float4 f1 = *reinterpret_cast<const float4*>(fm + kt + 16 + lgrp * 4);
      const float f0v[4] = {f0.x, f0.y, f0.z, f0.w};
      const float f1v[4] = {f1.x, f1.y, f1.z, f1.w};

      u16x8 pu;
      if (kt >= qw - 241 && kt <= qw + 225) {
#pragma unroll
        for (int r = 0; r < 4; ++r) {
          const float e0 = __builtin_amdgcn_exp2f(s0[r] + f0v[r]);
          const float e1 = __builtin_amdgcn_exp2f(s1[r] + f1v[r]);
          psum += e0 + e1;
          pu[r] = f2bf(e0);
          pu[4 + r] = f2bf(e1);
        }
      } else {
#pragma unroll
        for (int r = 0; r < 4; ++r) {
          const int key0 = kt + lgrp * 4 + r;
          const int d0 = key0 - q_abs + WIN;   // valid iff 0 <= d0 <= 2*WIN
          const float e0 = ((unsigned)d0 <= 2u * WIN) ? __builtin_amdgcn_exp2f(s0[r] + f0v[r]) : 0.f;
          const float e1 = ((unsigned)(d0 + 16) <= 2u * WIN) ? __builtin_amdgcn_exp2f(s1[r] + f1v[r]) : 0.f;
          psum += e0 + e1;
          pu[r] = f2bf(e0);
          pu[4 + r] = f2bf(e1);
        }
      }
      const bf16x8 pa = __builtin_bit_cast(bf16x8, pu);
      o_acc[0] = __builtin_amdgcn_mfma_f32_16x16x32_bf16(pa, vf0, o_acc[0], 0, 0, 0);
      o_acc[1] = __builtin_amdgcn_mfma_f32_16x16x32_bf16(pa, vf1, o_acc[1], 0, 0, 0);
      o_acc[2] = __builtin_amdgcn_mfma_f32_16x16x32_bf16(pa, vf2, o_acc[2], 0, 0, 0);
      o_acc[3] = __builtin_amdgcn_mfma_f32_16x16x32_bf16(pa, vf3, o_acc[3], 0, 0, 0);
    }
    if (t + 2 < NTT) { asm volatile("s_waitcnt vmcnt(1)" ::: "memory"); }
    else if (t + 1 < NTT) { asm volatile("s_waitcnt vmcnt(0)" ::: "memory"); }
    asm volatile("s_barrier" ::: "memory");
  }

  psum += __shfl_xor(psum, 16);
  psum += __shfl_xor(psum, 32);

  float psr[4];
#pragma unroll
  for (int r = 0; r < 4; ++r) psr[r] = __shfl(psum, lgrp * 4 + r, 64);
#pragma unroll
  for (int g = 0; g < 4; ++g)
#pragma unroll
    for (int r = 0; r < 4; ++r) {
      const int row = qw + lgrp * 4 + r;
      out[(size_t)row * DIM + h * HD + g * 16 + lrow] = o_acc[g][r] / psr[r];
    }
}

extern "C" void kernel_launch(void* const* d_in, const int* in_sizes, int n_in,
                              void* d_out, int out_size, void* d_ws, size_t ws_size,
                              hipStream_t stream) {
  const float* hsrc  = (const float*)d_in[0];
  const float* amask = (const float*)d_in[1];
  const float* Wq = (const float*)d_in[3];
  const float* bq = (const float*)d_in[4];
  const float* Wk = (const float*)d_in[5];
  const float* bk = (const float*)d_in[6];
  const float* Wv = (const float*)d_in[7];
  const float* bv = (const float*)d_in[8];
  float* out = (float*)d_out;
  char* ws = (char*)d_ws;
  const size_t MB = 1024 * 1024;
  u16*   Hb      = (u16*)(ws);                 // 8 MB: hidden bf16 [4096][1024]
  u16*   Wcat    = (u16*)(ws + 8 * MB);        // 6 MB: [3072][1024] bf16 (Wq|Wk|Wv)
  float* auxbuf  = (float*)(ws + 14 * MB);     // 28 KB: bias[3072] | fm[4096]
  u16*   Qh      = (u16*)(ws + 15 * MB);       // 8 MB: [NH][S][64] (pre-scaled by 0.125/ln2)
  u16*   Kh      = (u16*)(ws + 23 * MB);       // 8 MB: [NH][S][64]
  u16*   Vtile   = (u16*)(ws + 31 * MB);       // 8 MB: [NH][S/32][64][32] sigma-permuted

  cast_all<<<7196, 256, 0, stream>>>(hsrc, Wq, Wk, Wv, bq, bk, bv, amask, Hb, Wcat, auxbuf);

  dim3 gq(3 * DIM / 128, SEQ / 256);  // (24, 16) = 384 blocks
  gemm_qkv<<<gq, 256, 0, stream>>>(Hb, Wcat, auxbuf, Qh, Kh, Vtile);

  dim3 ga(SEQ / BQ, NH);              // (32, 16) -> 512 blocks x 8 waves
  lf_attn<<<ga, 512, 0, stream>>>(Qh, Kh, Vtile, auxbuf + 3072, out);
}